// Round 15
// baseline (195.919 us; speedup 1.0000x reference)
//
#include <hip/hip_runtime.h>
#include <math.h>

#define N_NODES 50000
#define N_EDGES 800000
#define DIM 64
#define HID 128
#define LAYERS 3
#define NGRAPH 128

#define SCAN_TILE 1024
#define SCAN_NB ((N_NODES + SCAN_TILE - 1) / SCAN_TILE)   // 49

typedef __attribute__((ext_vector_type(8))) short short8v;   // 8 bf16 (4 VGPR)
typedef __attribute__((ext_vector_type(4))) float f32x4;

__device__ __forceinline__ float bf2f(unsigned short u) {
    return __uint_as_float(((unsigned)u) << 16);
}
__device__ __forceinline__ unsigned short f2bf(float x) {
    unsigned u = __float_as_uint(x);
    unsigned r = (u + 0x7fff + ((u >> 16) & 1)) >> 16;   // RNE
    return (unsigned short)r;
}
// fast tanh: 1 - 2/(1+e^{2x}), clamp |x|<=9; err ~1e-6 << bf16 rounding
__device__ __forceinline__ float fast_tanh(float x) {
    float xc = fminf(fmaxf(x, -9.0f), 9.0f);
    float y = __expf(2.0f * xc);
    return 1.0f - 2.0f * __builtin_amdgcn_rcpf(y + 1.0f);
}

// ---------------------------------------------------------------------------
// attrs f32 -> bf16 (once): halves layer-0 gather bytes and its working set
// (12.8 MB f32 -> 6.4 MB bf16, closer to per-XCD L2 capacity).
// ---------------------------------------------------------------------------
__global__ void cvt_kernel(const float* __restrict__ a, unsigned short* __restrict__ b) {
    int i = blockIdx.x * blockDim.x + threadIdx.x;   // one short8 per thread
    if (i >= N_NODES * DIM / 8) return;
    const float4* p = reinterpret_cast<const float4*>(a + (size_t)i * 8);
    float4 u = p[0], w = p[1];
    short8v o;
    o[0] = (short)f2bf(u.x); o[1] = (short)f2bf(u.y);
    o[2] = (short)f2bf(u.z); o[3] = (short)f2bf(u.w);
    o[4] = (short)f2bf(w.x); o[5] = (short)f2bf(w.y);
    o[6] = (short)f2bf(w.z); o[7] = (short)f2bf(w.w);
    *reinterpret_cast<short8v*>(b + (size_t)i * 8) = o;
}

// ---------------------------------------------------------------------------
// CSR build. count records each edge's rank (atomicAdd return, u16) so place
// needs no atomic; x2 unroll keeps two atomic round-trips in flight.
// ---------------------------------------------------------------------------
__global__ void count_kernel(const int* __restrict__ dst,
                             int* __restrict__ counts,
                             unsigned short* __restrict__ rank) {
    int e = (blockIdx.x * blockDim.x + threadIdx.x) * 2;
    if (e + 1 < N_EDGES) {
        int d0 = dst[e], d1 = dst[e + 1];
        int r0 = atomicAdd(&counts[d0], 1);
        int r1 = atomicAdd(&counts[d1], 1);
        rank[e]     = (unsigned short)r0;
        rank[e + 1] = (unsigned short)r1;
    } else if (e < N_EDGES) {
        rank[e] = (unsigned short)atomicAdd(&counts[dst[e]], 1);
    }
}

__global__ void scan_partial_kernel(const int* __restrict__ counts,
                                    int* __restrict__ bsum) {
    __shared__ int red[256];
    const int b = blockIdx.x, tid = threadIdx.x;
    const int base = b * SCAN_TILE + tid * 4;
    int s = 0;
    if (base + 3 < N_NODES) {
        int4 v = *reinterpret_cast<const int4*>(counts + base);
        s = v.x + v.y + v.z + v.w;
    } else {
        for (int i = 0; i < 4; ++i)
            if (base + i < N_NODES) s += counts[base + i];
    }
    red[tid] = s;
    __syncthreads();
    for (int off = 128; off > 0; off >>= 1) {
        if (tid < off) red[tid] += red[tid + off];
        __syncthreads();
    }
    if (tid == 0) bsum[b] = red[0];
}

// scan_final also computes its block's global prefix from bsum (49 ints = 4
// cache lines) -- the separate scan_mid dispatch is gone.
__global__ void scan_final_kernel(const int* __restrict__ counts,
                                  const int* __restrict__ bsum,
                                  int* __restrict__ offsets) {
    __shared__ int pre[256];
    __shared__ int bbase;
    const int b = blockIdx.x, tid = threadIdx.x;
    if (tid == 0) {
        int s = 0;
        for (int i = 0; i < b; ++i) s += bsum[i];
        bbase = s;
        if (b == SCAN_NB - 1) offsets[N_NODES] = N_EDGES;
    }
    const int base = b * SCAN_TILE + tid * 4;
    int c[4];
    int s = 0;
#pragma unroll
    for (int i = 0; i < 4; ++i) {
        c[i] = (base + i < N_NODES) ? counts[base + i] : 0;
        s += c[i];
    }
    pre[tid] = s;
    __syncthreads();
    for (int off = 1; off < 256; off <<= 1) {
        int v = (tid >= off) ? pre[tid - off] : 0;
        __syncthreads();
        pre[tid] += v;
        __syncthreads();
    }
    int run = bbase + pre[tid] - s;
#pragma unroll
    for (int i = 0; i < 4; ++i) {
        if (base + i < N_NODES) {
            offsets[base + i] = run;
            run += c[i];
        }
    }
}

__global__ void place_kernel(const int* __restrict__ src,
                             const int* __restrict__ dst,
                             const unsigned short* __restrict__ rank,
                             const int* __restrict__ offsets,
                             unsigned short* __restrict__ csr_src) {
    int e = (blockIdx.x * blockDim.x + threadIdx.x) * 2;
    if (e + 1 < N_EDGES) {
        int d0 = dst[e], d1 = dst[e + 1];
        int o0 = offsets[d0], o1 = offsets[d1];      // two gathers in flight
        csr_src[o0 + (int)rank[e]]     = (unsigned short)src[e];
        csr_src[o1 + (int)rank[e + 1]] = (unsigned short)src[e + 1];
    } else if (e < N_EDGES) {
        csr_src[offsets[dst[e]] + (int)rank[e]] = (unsigned short)src[e];
    }
}

// ---------------------------------------------------------------------------
// weight repack: W[L][K][C] f32 -> frag-major bf16 P[L][KT][CT][64 lanes][8]
// lane l (li=l&15, hi=l>>4) gets W[kt*32 + hi*8 + j][ct*16 + li], j=0..7
// ---------------------------------------------------------------------------
template<int K, int C>
__device__ __forceinline__ void repack_one(const float* __restrict__ W,
                                           unsigned short* __restrict__ P, int t) {
    constexpr int KT = K / 32, CT = C / 16;
    int lane = t & 63; int rest = t >> 6;
    int ct = rest % CT; rest /= CT;
    int kt = rest % KT; int l = rest / KT;
    int li = lane & 15, hi = lane >> 4;
    const float* Wl = W + (size_t)l * K * C;
    short8v o;
#pragma unroll
    for (int j = 0; j < 8; ++j)
        o[j] = (short)f2bf(Wl[(size_t)(kt * 32 + hi * 8 + j) * C + ct * 16 + li]);
    *reinterpret_cast<short8v*>(P + ((size_t)l * KT * CT * 64 + (size_t)(kt * CT + ct) * 64 + lane) * 8) = o;
}

__global__ void repack_all_kernel(const float* __restrict__ W1, const float* __restrict__ W2,
                                  const float* __restrict__ W3,
                                  unsigned short* __restrict__ P1, unsigned short* __restrict__ P2,
                                  unsigned short* __restrict__ P3) {
    int t = blockIdx.x * 256 + threadIdx.x;       // 12288 total
    if (t < 3072)       repack_one<DIM, HID>(W1, P1, t);
    else if (t < 9216)  repack_one<HID, HID>(W2, P2, t - 3072);
    else                repack_one<HID, DIM>(W3, P3, t - 9216);
}

// ---------------------------------------------------------------------------
// fused GIN layer, 512 threads (r15): 16 rows/block; gather uses 4 edge-
// quarter groups x 8 lanes x 16 B per node (serial depth ~deg/4); 4 partial
// f32 LDS tiles (no atomics), A-frag sums them. MLP: 8 waves C-split
// (gemm1/2: ct = wave; gemm3: waves 0-3). LAST layer fuses mean-pool
// (run-compressed f32 atomics into psums). IN/OUT distinct (round-6 race).
// Frag conv: k = kt*32+hi*8+j, row/col = li. D conv (m89): col=li,
// row=hi*4+j. tileA/B swizzle byte^=(row&7)<<4. agg stride 68 floats.
// ---------------------------------------------------------------------------
template<bool LAST>
__global__ __launch_bounds__(512) void gnn_layer_kernel(
        const unsigned short* __restrict__ xb,
        const int* __restrict__ offsets, const unsigned short* __restrict__ csr_src,
        const unsigned short* __restrict__ pw1, const float* __restrict__ bias1,
        const unsigned short* __restrict__ pw2, const float* __restrict__ bias2,
        const unsigned short* __restrict__ pw3, const float* __restrict__ bias3,
        unsigned short* __restrict__ outx,
        const int* __restrict__ batch, float* __restrict__ psums) {
    __shared__ float aggQ[4][16 * 68];           // 17 KB, 4 edge-quarters
    __shared__ unsigned short tileA[16 * 128];   // 4 KB
    __shared__ unsigned short tileB[16 * 128];   // 4 KB
    __shared__ int soff[17];
    const int tid = threadIdx.x;
    const int wave = tid >> 6, lane = tid & 63;
    const int li = lane & 15, hi = lane >> 4;
    const int r0 = blockIdx.x * 16;              // 3125*16 == N exactly
    char* tA = reinterpret_cast<char*>(tileA);
    char* tB = reinterpret_cast<char*>(tileB);

    if (tid < 17) soff[tid] = offsets[r0 + tid];
    __syncthreads();

    // ---- gather: group = 8 lanes; node nr = g>>2, quarter h = g&3 ----
    {
        const int g  = tid >> 3;                 // 0..63
        const int nr = g >> 2;                   // node row 0..15
        const int h  = g & 3;                    // edge quarter
        const int q  = tid & 7;                  // channel oct (8 ch, 16 B)
        const int n  = r0 + nr;
        float a[8];
        if (h == 0) {                            // seed with self row
            short8v v = *reinterpret_cast<const short8v*>(xb + (size_t)n * DIM + q * 8);
#pragma unroll
            for (int j = 0; j < 8; ++j) a[j] = bf2f((unsigned short)v[j]);
        } else {
#pragma unroll
            for (int j = 0; j < 8; ++j) a[j] = 0.f;
        }
        const int p0 = soff[nr];
        const int d  = soff[nr + 1] - p0;
        int p        = p0 + ((d * h) >> 2);
        const int pe = p0 + ((d * (h + 1)) >> 2);
        for (; p + 4 <= pe; p += 4) {
            int s0 = csr_src[p + 0];
            int s1 = csr_src[p + 1];
            int s2 = csr_src[p + 2];
            int s3 = csr_src[p + 3];
            short8v v0 = *reinterpret_cast<const short8v*>(xb + (size_t)s0 * DIM + q * 8);
            short8v v1 = *reinterpret_cast<const short8v*>(xb + (size_t)s1 * DIM + q * 8);
            short8v v2 = *reinterpret_cast<const short8v*>(xb + (size_t)s2 * DIM + q * 8);
            short8v v3 = *reinterpret_cast<const short8v*>(xb + (size_t)s3 * DIM + q * 8);
#pragma unroll
            for (int j = 0; j < 8; ++j)
                a[j] += bf2f((unsigned short)v0[j]) + bf2f((unsigned short)v1[j])
                      + bf2f((unsigned short)v2[j]) + bf2f((unsigned short)v3[j]);
        }
        for (; p < pe; ++p) {
            int s = csr_src[p];
            short8v v = *reinterpret_cast<const short8v*>(xb + (size_t)s * DIM + q * 8);
#pragma unroll
            for (int j = 0; j < 8; ++j) a[j] += bf2f((unsigned short)v[j]);
        }
        float* dq = &aggQ[h][nr * 68 + q * 8];
        *reinterpret_cast<f32x4*>(dq)     = (f32x4){a[0], a[1], a[2], a[3]};
        *reinterpret_cast<f32x4*>(dq + 4) = (f32x4){a[4], a[5], a[6], a[7]};
    }
    __syncthreads();

    // ---- A-frags: sum the four quarters (row = li, k = kt*32 + hi*8 + j) ----
    short8v af[2];
#pragma unroll
    for (int kt = 0; kt < 2; ++kt) {
        const float* s0 = &aggQ[0][li * 68 + kt * 32 + hi * 8];
        const float* s1 = &aggQ[1][li * 68 + kt * 32 + hi * 8];
        const float* s2 = &aggQ[2][li * 68 + kt * 32 + hi * 8];
        const float* s3 = &aggQ[3][li * 68 + kt * 32 + hi * 8];
#pragma unroll
        for (int j = 0; j < 8; ++j)
            af[kt][j] = (short)f2bf((s0[j] + s1[j]) + (s2[j] + s3[j]));
    }

    // ---- gemm1: K=64, C=128; wave owns ct = wave ----
    {
        const int ct = wave;
        f32x4 acc1 = (f32x4){0.f, 0.f, 0.f, 0.f};
#pragma unroll
        for (int kt = 0; kt < 2; ++kt) {
            short8v bfr = *reinterpret_cast<const short8v*>(pw1 + ((size_t)(kt * 8 + ct) * 64 + lane) * 8);
            acc1 = __builtin_amdgcn_mfma_f32_16x16x32_bf16(af[kt], bfr, acc1, 0, 0, 0);
        }
        float bv = bias1[ct * 16 + li];
#pragma unroll
        for (int j = 0; j < 4; ++j) {
            int row = hi * 4 + j;
            unsigned off = (unsigned)(row * 256 + (ct * 16 + li) * 2) ^ ((unsigned)(row & 7) << 4);
            *reinterpret_cast<unsigned short*>(tA + off) = f2bf(fast_tanh(acc1[j] + bv));
        }
    }
    __syncthreads();

    // ---- gemm2: K=128, C=128; wave owns ct = wave ----
    short8v af2[4];
#pragma unroll
    for (int kt = 0; kt < 4; ++kt) {
        unsigned off = (unsigned)(li * 256 + (kt * 32 + hi * 8) * 2) ^ ((unsigned)(li & 7) << 4);
        af2[kt] = *reinterpret_cast<const short8v*>(tA + off);
    }
    {
        const int ct = wave;
        f32x4 acc2 = (f32x4){0.f, 0.f, 0.f, 0.f};
#pragma unroll
        for (int kt = 0; kt < 4; ++kt) {
            short8v bfr = *reinterpret_cast<const short8v*>(pw2 + ((size_t)(kt * 8 + ct) * 64 + lane) * 8);
            acc2 = __builtin_amdgcn_mfma_f32_16x16x32_bf16(af2[kt], bfr, acc2, 0, 0, 0);
        }
        float bv = bias2[ct * 16 + li];
#pragma unroll
        for (int j = 0; j < 4; ++j) {
            int row = hi * 4 + j;
            unsigned off = (unsigned)(row * 256 + (ct * 16 + li) * 2) ^ ((unsigned)(row & 7) << 4);
            *reinterpret_cast<unsigned short*>(tB + off) = f2bf(fast_tanh(acc2[j] + bv));
        }
    }
    __syncthreads();

    // ---- gemm3: K=128, C=64; waves 0-3 own ct = wave ----
    if (wave < 4) {
        short8v af3[4];
#pragma unroll
        for (int kt = 0; kt < 4; ++kt) {
            unsigned off = (unsigned)(li * 256 + (kt * 32 + hi * 8) * 2) ^ ((unsigned)(li & 7) << 4);
            af3[kt] = *reinterpret_cast<const short8v*>(tB + off);
        }
        f32x4 acc3 = (f32x4){0.f, 0.f, 0.f, 0.f};
#pragma unroll
        for (int kt = 0; kt < 4; ++kt) {
            short8v bfr = *reinterpret_cast<const short8v*>(pw3 + ((size_t)(kt * 4 + wave) * 64 + lane) * 8);
            acc3 = __builtin_amdgcn_mfma_f32_16x16x32_bf16(af3[kt], bfr, acc3, 0, 0, 0);
        }
        const int c = wave * 16 + li;
        float bv = bias3[c];
        if (LAST) {
            const int row0 = r0 + hi * 4;
            float v[4];
#pragma unroll
            for (int j = 0; j < 4; ++j) v[j] = fast_tanh(fast_tanh(acc3[j] + bv));
            int g = batch[row0];
            float acc = v[0];
#pragma unroll
            for (int j = 1; j < 4; ++j) {
                int gj = batch[row0 + j];
                if (gj == g) acc += v[j];
                else {
                    atomicAdd(&psums[g * DIM + c], acc);
                    g = gj; acc = v[j];
                }
            }
            atomicAdd(&psums[g * DIM + c], acc);
        } else {
#pragma unroll
            for (int j = 0; j < 4; ++j) {
                int row = r0 + hi * 4 + j;
                float vv = fast_tanh(fast_tanh(acc3[j] + bv));
                outx[(size_t)row * DIM + c] = f2bf(vv);
            }
        }
    }
}

// out[g][d] = psums[g][d] / count(g); count via binary search (batch sorted)
__global__ void pool_final_kernel(const float* __restrict__ sums,
                                  const int* __restrict__ batch,
                                  float* __restrict__ out) {
    const int g = blockIdx.x;
    const int d = threadIdx.x;
    int lo = 0, hi = N_NODES;
    while (lo < hi) { int m = (lo + hi) >> 1; if (batch[m] < g) lo = m + 1; else hi = m; }
    int start = lo;
    hi = N_NODES;
    while (lo < hi) { int m = (lo + hi) >> 1; if (batch[m] < g + 1) lo = m + 1; else hi = m; }
    float cnt = (float)(lo - start);
    out[g * DIM + d] = sums[g * DIM + d] / fmaxf(cnt, 1.f);
}

// ---------------------------------------------------------------------------
extern "C" void kernel_launch(void* const* d_in, const int* in_sizes, int n_in,
                              void* d_out, int out_size, void* d_ws, size_t ws_size,
                              hipStream_t stream) {
    const float* attrs = (const float*)d_in[0];
    const float* W1    = (const float*)d_in[1];
    const float* b1    = (const float*)d_in[2];
    const float* W2    = (const float*)d_in[3];
    const float* b2    = (const float*)d_in[4];
    const float* W3    = (const float*)d_in[5];
    const float* b3    = (const float*)d_in[6];
    const int* edge_index = (const int*)d_in[7];
    const int* batch      = (const int*)d_in[8];
    float* out = (float*)d_out;

    unsigned short* buf0   = (unsigned short*)d_ws;             // N*64 bf16
    unsigned short* buf1   = buf0 + (size_t)N_NODES * DIM;      // N*64 bf16
    unsigned short* attrsb = buf1 + (size_t)N_NODES * DIM;      // N*64 bf16
    unsigned short* pW1  = attrsb + (size_t)N_NODES * DIM;      // 24576
    unsigned short* pW2  = pW1 + 24576;                         // 49152
    unsigned short* pW3  = pW2 + 49152;                         // 24576
    float* psums  = (float*)(pW3 + 24576);                      // G*64 f32
    int* offsets  = (int*)(psums + NGRAPH * DIM);               // N+1
    unsigned short* csr16 = (unsigned short*)(offsets + N_NODES + 1);  // E u16
    unsigned short* rank  = csr16 + N_EDGES;                    // E u16
    int* counts   = (int*)(rank + N_EDGES);                     // N
    int* bsum     = counts + N_NODES;                           // SCAN_NB

    const int* src = edge_index;
    const int* dst = edge_index + N_EDGES;

    const int pair_blocks = (N_EDGES / 2 + 255) / 256;
    const int gnn_blocks  = N_NODES / 16;                       // 3125, exact
    const int cvt_blocks  = (N_NODES * DIM / 8 + 255) / 256;

    // ---- one-time prep ----
    hipMemsetAsync(counts, 0, (size_t)N_NODES * sizeof(int), stream);
    hipMemsetAsync(psums, 0, (size_t)NGRAPH * DIM * sizeof(float), stream);
    cvt_kernel<<<cvt_blocks, 256, 0, stream>>>(attrs, attrsb);
    count_kernel<<<pair_blocks, 256, 0, stream>>>(dst, counts, rank);
    scan_partial_kernel<<<SCAN_NB, 256, 0, stream>>>(counts, bsum);
    scan_final_kernel<<<SCAN_NB, 256, 0, stream>>>(counts, bsum, offsets);
    place_kernel<<<pair_blocks, 256, 0, stream>>>(src, dst, rank, offsets, csr16);
    repack_all_kernel<<<48, 256, 0, stream>>>(W1, W2, W3, pW1, pW2, pW3);

    // ---- fused layers: attrsb -> buf0 -> buf1 -> psums (pool fused) ----
    for (int l = 0; l < LAYERS; ++l) {
        const unsigned short* w1 = pW1 + (size_t)l * 2 * 8 * 64 * 8;
        const unsigned short* w2 = pW2 + (size_t)l * 4 * 8 * 64 * 8;
        const unsigned short* w3 = pW3 + (size_t)l * 4 * 4 * 64 * 8;
        const float* bb1 = b1 + (size_t)l * HID;
        const float* bb2 = b2 + (size_t)l * HID;
        const float* bb3 = b3 + (size_t)l * DIM;
        if (l == 0)
            gnn_layer_kernel<false><<<gnn_blocks, 512, 0, stream>>>(
                attrsb, offsets, csr16, w1, bb1, w2, bb2, w3, bb3,
                buf0, nullptr, nullptr);
        else if (l == 1)
            gnn_layer_kernel<false><<<gnn_blocks, 512, 0, stream>>>(
                buf0, offsets, csr16, w1, bb1, w2, bb2, w3, bb3,
                buf1, nullptr, nullptr);
        else
            gnn_layer_kernel<true><<<gnn_blocks, 512, 0, stream>>>(
                buf1, offsets, csr16, w1, bb1, w2, bb2, w3, bb3,
                nullptr, batch, psums);
    }

    // ---- finalize mean pool ----
    pool_final_kernel<<<NGRAPH, DIM, 0, stream>>>(psums, batch, out);
}

// Round 16
// 176.548 us; speedup vs baseline: 1.1097x; 1.1097x over previous
//
#include <hip/hip_runtime.h>
#include <math.h>

#define N_NODES 50000
#define N_EDGES 800000
#define DIM 64
#define HID 128
#define LAYERS 3
#define NGRAPH 128

#define SCAN_TILE 1024
#define SCAN_NB ((N_NODES + SCAN_TILE - 1) / SCAN_TILE)   // 49

typedef __attribute__((ext_vector_type(8))) short short8v;   // 8 bf16 (4 VGPR)
typedef __attribute__((ext_vector_type(4))) float f32x4;

__device__ __forceinline__ float bf2f(unsigned short u) {
    return __uint_as_float(((unsigned)u) << 16);
}
__device__ __forceinline__ unsigned short f2bf(float x) {
    unsigned u = __float_as_uint(x);
    unsigned r = (u + 0x7fff + ((u >> 16) & 1)) >> 16;   // RNE
    return (unsigned short)r;
}
// fast tanh: 1 - 2/(1+e^{2x}), clamp |x|<=9; err ~1e-6 << bf16 rounding
__device__ __forceinline__ float fast_tanh(float x) {
    float xc = fminf(fmaxf(x, -9.0f), 9.0f);
    float y = __expf(2.0f * xc);
    return 1.0f - 2.0f * __builtin_amdgcn_rcpf(y + 1.0f);
}

// ---------------------------------------------------------------------------
// attrs f32 -> bf16 (once): layer-0 gather working set 12.8 -> 6.4 MB
// ---------------------------------------------------------------------------
__global__ void cvt_kernel(const float* __restrict__ a, unsigned short* __restrict__ b) {
    int i = blockIdx.x * blockDim.x + threadIdx.x;   // one short8 per thread
    if (i >= N_NODES * DIM / 8) return;
    const float4* p = reinterpret_cast<const float4*>(a + (size_t)i * 8);
    float4 u = p[0], w = p[1];
    short8v o;
    o[0] = (short)f2bf(u.x); o[1] = (short)f2bf(u.y);
    o[2] = (short)f2bf(u.z); o[3] = (short)f2bf(u.w);
    o[4] = (short)f2bf(w.x); o[5] = (short)f2bf(w.y);
    o[6] = (short)f2bf(w.z); o[7] = (short)f2bf(w.w);
    *reinterpret_cast<short8v*>(b + (size_t)i * 8) = o;
}

// ---------------------------------------------------------------------------
// CSR build. count records each edge's rank (atomicAdd return, u16) so place
// needs no atomic; x2 unroll keeps two atomic round-trips in flight.
// ---------------------------------------------------------------------------
__global__ void count_kernel(const int* __restrict__ dst,
                             int* __restrict__ counts,
                             unsigned short* __restrict__ rank) {
    int e = (blockIdx.x * blockDim.x + threadIdx.x) * 2;
    if (e + 1 < N_EDGES) {
        int d0 = dst[e], d1 = dst[e + 1];
        int r0 = atomicAdd(&counts[d0], 1);
        int r1 = atomicAdd(&counts[d1], 1);
        rank[e]     = (unsigned short)r0;
        rank[e + 1] = (unsigned short)r1;
    } else if (e < N_EDGES) {
        rank[e] = (unsigned short)atomicAdd(&counts[dst[e]], 1);
    }
}

__global__ void scan_partial_kernel(const int* __restrict__ counts,
                                    int* __restrict__ bsum) {
    __shared__ int red[256];
    const int b = blockIdx.x, tid = threadIdx.x;
    const int base = b * SCAN_TILE + tid * 4;
    int s = 0;
    if (base + 3 < N_NODES) {
        int4 v = *reinterpret_cast<const int4*>(counts + base);
        s = v.x + v.y + v.z + v.w;
    } else {
        for (int i = 0; i < 4; ++i)
            if (base + i < N_NODES) s += counts[base + i];
    }
    red[tid] = s;
    __syncthreads();
    for (int off = 128; off > 0; off >>= 1) {
        if (tid < off) red[tid] += red[tid + off];
        __syncthreads();
    }
    if (tid == 0) bsum[b] = red[0];
}

// scan_final computes its block's global prefix from bsum inline (49 ints)
__global__ void scan_final_kernel(const int* __restrict__ counts,
                                  const int* __restrict__ bsum,
                                  int* __restrict__ offsets) {
    __shared__ int pre[256];
    __shared__ int bbase;
    const int b = blockIdx.x, tid = threadIdx.x;
    if (tid == 0) {
        int s = 0;
        for (int i = 0; i < b; ++i) s += bsum[i];
        bbase = s;
        if (b == SCAN_NB - 1) offsets[N_NODES] = N_EDGES;
    }
    const int base = b * SCAN_TILE + tid * 4;
    int c[4];
    int s = 0;
#pragma unroll
    for (int i = 0; i < 4; ++i) {
        c[i] = (base + i < N_NODES) ? counts[base + i] : 0;
        s += c[i];
    }
    pre[tid] = s;
    __syncthreads();
    for (int off = 1; off < 256; off <<= 1) {
        int v = (tid >= off) ? pre[tid - off] : 0;
        __syncthreads();
        pre[tid] += v;
        __syncthreads();
    }
    int run = bbase + pre[tid] - s;
#pragma unroll
    for (int i = 0; i < 4; ++i) {
        if (base + i < N_NODES) {
            offsets[base + i] = run;
            run += c[i];
        }
    }
}

__global__ void place_kernel(const int* __restrict__ src,
                             const int* __restrict__ dst,
                             const unsigned short* __restrict__ rank,
                             const int* __restrict__ offsets,
                             unsigned short* __restrict__ csr_src) {
    int e = (blockIdx.x * blockDim.x + threadIdx.x) * 2;
    if (e + 1 < N_EDGES) {
        int d0 = dst[e], d1 = dst[e + 1];
        int o0 = offsets[d0], o1 = offsets[d1];      // two gathers in flight
        csr_src[o0 + (int)rank[e]]     = (unsigned short)src[e];
        csr_src[o1 + (int)rank[e + 1]] = (unsigned short)src[e + 1];
    } else if (e < N_EDGES) {
        csr_src[offsets[dst[e]] + (int)rank[e]] = (unsigned short)src[e];
    }
}

// ---------------------------------------------------------------------------
// weight repack: W[L][K][C] f32 -> frag-major bf16 P[L][KT][CT][64 lanes][8]
// lane l (li=l&15, hi=l>>4) gets W[kt*32 + hi*8 + j][ct*16 + li], j=0..7
// ---------------------------------------------------------------------------
template<int K, int C>
__device__ __forceinline__ void repack_one(const float* __restrict__ W,
                                           unsigned short* __restrict__ P, int t) {
    constexpr int KT = K / 32, CT = C / 16;
    int lane = t & 63; int rest = t >> 6;
    int ct = rest % CT; rest /= CT;
    int kt = rest % KT; int l = rest / KT;
    int li = lane & 15, hi = lane >> 4;
    const float* Wl = W + (size_t)l * K * C;
    short8v o;
#pragma unroll
    for (int j = 0; j < 8; ++j)
        o[j] = (short)f2bf(Wl[(size_t)(kt * 32 + hi * 8 + j) * C + ct * 16 + li]);
    *reinterpret_cast<short8v*>(P + ((size_t)l * KT * CT * 64 + (size_t)(kt * CT + ct) * 64 + lane) * 8) = o;
}

__global__ void repack_all_kernel(const float* __restrict__ W1, const float* __restrict__ W2,
                                  const float* __restrict__ W3,
                                  unsigned short* __restrict__ P1, unsigned short* __restrict__ P2,
                                  unsigned short* __restrict__ P3) {
    int t = blockIdx.x * 256 + threadIdx.x;       // 12288 total
    if (t < 3072)       repack_one<DIM, HID>(W1, P1, t);
    else if (t < 9216)  repack_one<HID, HID>(W2, P2, t - 3072);
    else                repack_one<HID, DIM>(W3, P3, t - 9216);
}

// ---------------------------------------------------------------------------
// fused GIN layer (round-14 structure, all-bf16): 256 threads, 16 rows.
// Gather: per node, TWO groups of 8 lanes walk static halves (~8 edges each,
// so the unroll-4 body actually executes; round-15's quarters were too short).
// Halves -> two f32 LDS tiles (no atomics); A-frag sums them.
// MLP: 4 waves C-split (gemm1/2: ct = 2w+{0,1}; gemm3: ct = w).
// LAST layer fuses mean-pool (run-compressed f32 atomics into psums).
// IN/OUT distinct (round-6 race). Frag conv: k = kt*32+hi*8+j, row/col = li.
// D conv (m89): col=li, row=hi*4+j. tileA/B swizzle byte^=(row&7)<<4.
// agg tiles stride 68 floats.
// ---------------------------------------------------------------------------
template<bool LAST>
__global__ __launch_bounds__(256) void gnn_layer_kernel(
        const unsigned short* __restrict__ xb,
        const int* __restrict__ offsets, const unsigned short* __restrict__ csr_src,
        const unsigned short* __restrict__ pw1, const float* __restrict__ bias1,
        const unsigned short* __restrict__ pw2, const float* __restrict__ bias2,
        const unsigned short* __restrict__ pw3, const float* __restrict__ bias3,
        unsigned short* __restrict__ outx,
        const int* __restrict__ batch, float* __restrict__ psums) {
    __shared__ float aggA[16 * 68];              // 4.25 KB, half 0 (+self)
    __shared__ float aggB[16 * 68];              // 4.25 KB, half 1
    __shared__ unsigned short tileA[16 * 128];   // 4 KB
    __shared__ unsigned short tileB[16 * 128];   // 4 KB
    __shared__ int soff[17];
    const int tid = threadIdx.x;
    const int wave = tid >> 6, lane = tid & 63;
    const int li = lane & 15, hi = lane >> 4;
    const int r0 = blockIdx.x * 16;              // 3125*16 == N exactly
    char* tA = reinterpret_cast<char*>(tileA);
    char* tB = reinterpret_cast<char*>(tileB);

    if (tid < 17) soff[tid] = offsets[r0 + tid];
    __syncthreads();

    // ---- gather: group = 8 lanes; node nr = group>>1, half h = group&1 ----
    {
        const int g  = tid >> 3;                 // 0..31
        const int nr = g >> 1;                   // node row 0..15
        const int h  = g & 1;
        const int q  = tid & 7;                  // channel oct (8 ch, 16 B)
        const int n  = r0 + nr;
        float a[8];
        if (h == 0) {                            // seed with self row
            short8v v = *reinterpret_cast<const short8v*>(xb + (size_t)n * DIM + q * 8);
#pragma unroll
            for (int j = 0; j < 8; ++j) a[j] = bf2f((unsigned short)v[j]);
        } else {
#pragma unroll
            for (int j = 0; j < 8; ++j) a[j] = 0.f;
        }
        const int p0 = soff[nr], pe1 = soff[nr + 1];
        const int mid = p0 + ((pe1 - p0 + 1) >> 1);
        int p        = h ? mid : p0;
        const int pe = h ? pe1 : mid;
        for (; p + 4 <= pe; p += 4) {
            int s0 = csr_src[p + 0];
            int s1 = csr_src[p + 1];
            int s2 = csr_src[p + 2];
            int s3 = csr_src[p + 3];
            short8v v0 = *reinterpret_cast<const short8v*>(xb + (size_t)s0 * DIM + q * 8);
            short8v v1 = *reinterpret_cast<const short8v*>(xb + (size_t)s1 * DIM + q * 8);
            short8v v2 = *reinterpret_cast<const short8v*>(xb + (size_t)s2 * DIM + q * 8);
            short8v v3 = *reinterpret_cast<const short8v*>(xb + (size_t)s3 * DIM + q * 8);
#pragma unroll
            for (int j = 0; j < 8; ++j)
                a[j] += bf2f((unsigned short)v0[j]) + bf2f((unsigned short)v1[j])
                      + bf2f((unsigned short)v2[j]) + bf2f((unsigned short)v3[j]);
        }
        for (; p < pe; ++p) {
            int s = csr_src[p];
            short8v v = *reinterpret_cast<const short8v*>(xb + (size_t)s * DIM + q * 8);
#pragma unroll
            for (int j = 0; j < 8; ++j) a[j] += bf2f((unsigned short)v[j]);
        }
        float* d = (h ? aggB : aggA) + nr * 68 + q * 8;
        *reinterpret_cast<f32x4*>(d)     = (f32x4){a[0], a[1], a[2], a[3]};
        *reinterpret_cast<f32x4*>(d + 4) = (f32x4){a[4], a[5], a[6], a[7]};
    }
    __syncthreads();

    // ---- A-frags: sum the two halves (row = li, k = kt*32 + hi*8 + j) ----
    short8v af[2];
#pragma unroll
    for (int kt = 0; kt < 2; ++kt) {
        const float* sA = &aggA[li * 68 + kt * 32 + hi * 8];
        const float* sB = &aggB[li * 68 + kt * 32 + hi * 8];
#pragma unroll
        for (int j = 0; j < 8; ++j) af[kt][j] = (short)f2bf(sA[j] + sB[j]);
    }

    // ---- gemm1: K=64, C=128; wave owns ct = 2*wave + {0,1} ----
    f32x4 acc1[2];
#pragma unroll
    for (int c = 0; c < 2; ++c) acc1[c] = (f32x4){0.f, 0.f, 0.f, 0.f};
#pragma unroll
    for (int c = 0; c < 2; ++c) {
        const int ct = 2 * wave + c;
#pragma unroll
        for (int kt = 0; kt < 2; ++kt) {
            short8v bfr = *reinterpret_cast<const short8v*>(pw1 + ((size_t)(kt * 8 + ct) * 64 + lane) * 8);
            acc1[c] = __builtin_amdgcn_mfma_f32_16x16x32_bf16(af[kt], bfr, acc1[c], 0, 0, 0);
        }
    }
#pragma unroll
    for (int c = 0; c < 2; ++c) {
        const int ct = 2 * wave + c;
        float bv = bias1[ct * 16 + li];
#pragma unroll
        for (int j = 0; j < 4; ++j) {
            int row = hi * 4 + j;
            unsigned off = (unsigned)(row * 256 + (ct * 16 + li) * 2) ^ ((unsigned)(row & 7) << 4);
            *reinterpret_cast<unsigned short*>(tA + off) = f2bf(fast_tanh(acc1[c][j] + bv));
        }
    }
    __syncthreads();

    // ---- gemm2: K=128, C=128 ----
    short8v af2[4];
#pragma unroll
    for (int kt = 0; kt < 4; ++kt) {
        unsigned off = (unsigned)(li * 256 + (kt * 32 + hi * 8) * 2) ^ ((unsigned)(li & 7) << 4);
        af2[kt] = *reinterpret_cast<const short8v*>(tA + off);
    }
    f32x4 acc2[2];
#pragma unroll
    for (int c = 0; c < 2; ++c) acc2[c] = (f32x4){0.f, 0.f, 0.f, 0.f};
#pragma unroll
    for (int c = 0; c < 2; ++c) {
        const int ct = 2 * wave + c;
#pragma unroll
        for (int kt = 0; kt < 4; ++kt) {
            short8v bfr = *reinterpret_cast<const short8v*>(pw2 + ((size_t)(kt * 8 + ct) * 64 + lane) * 8);
            acc2[c] = __builtin_amdgcn_mfma_f32_16x16x32_bf16(af2[kt], bfr, acc2[c], 0, 0, 0);
        }
    }
#pragma unroll
    for (int c = 0; c < 2; ++c) {
        const int ct = 2 * wave + c;
        float bv = bias2[ct * 16 + li];
#pragma unroll
        for (int j = 0; j < 4; ++j) {
            int row = hi * 4 + j;
            unsigned off = (unsigned)(row * 256 + (ct * 16 + li) * 2) ^ ((unsigned)(row & 7) << 4);
            *reinterpret_cast<unsigned short*>(tB + off) = f2bf(fast_tanh(acc2[c][j] + bv));
        }
    }
    __syncthreads();

    // ---- gemm3: K=128, C=64; wave owns ct = wave ----
    short8v af3[4];
#pragma unroll
    for (int kt = 0; kt < 4; ++kt) {
        unsigned off = (unsigned)(li * 256 + (kt * 32 + hi * 8) * 2) ^ ((unsigned)(li & 7) << 4);
        af3[kt] = *reinterpret_cast<const short8v*>(tB + off);
    }
    f32x4 acc3 = (f32x4){0.f, 0.f, 0.f, 0.f};
#pragma unroll
    for (int kt = 0; kt < 4; ++kt) {
        short8v bfr = *reinterpret_cast<const short8v*>(pw3 + ((size_t)(kt * 4 + wave) * 64 + lane) * 8);
        acc3 = __builtin_amdgcn_mfma_f32_16x16x32_bf16(af3[kt], bfr, acc3, 0, 0, 0);
    }
    {
        const int c = wave * 16 + li;
        float bv = bias3[c];
        if (LAST) {
            // fused mean-pool partial: run-compress the 4 consecutive rows
            // (batch sorted) and atomicAdd f32 partials into psums[g][c].
            const int row0 = r0 + hi * 4;
            float v[4];
#pragma unroll
            for (int j = 0; j < 4; ++j) v[j] = fast_tanh(fast_tanh(acc3[j] + bv));
            int g = batch[row0];
            float acc = v[0];
#pragma unroll
            for (int j = 1; j < 4; ++j) {
                int gj = batch[row0 + j];
                if (gj == g) acc += v[j];
                else {
                    atomicAdd(&psums[g * DIM + c], acc);
                    g = gj; acc = v[j];
                }
            }
            atomicAdd(&psums[g * DIM + c], acc);
        } else {
#pragma unroll
            for (int j = 0; j < 4; ++j) {
                int row = r0 + hi * 4 + j;
                float vv = fast_tanh(fast_tanh(acc3[j] + bv));
                outx[(size_t)row * DIM + c] = f2bf(vv);
            }
        }
    }
}

// out[g][d] = psums[g][d] / count(g); count via binary search (batch sorted)
__global__ void pool_final_kernel(const float* __restrict__ sums,
                                  const int* __restrict__ batch,
                                  float* __restrict__ out) {
    const int g = blockIdx.x;
    const int d = threadIdx.x;
    int lo = 0, hi = N_NODES;
    while (lo < hi) { int m = (lo + hi) >> 1; if (batch[m] < g) lo = m + 1; else hi = m; }
    int start = lo;
    hi = N_NODES;
    while (lo < hi) { int m = (lo + hi) >> 1; if (batch[m] < g + 1) lo = m + 1; else hi = m; }
    float cnt = (float)(lo - start);
    out[g * DIM + d] = sums[g * DIM + d] / fmaxf(cnt, 1.f);
}

// ---------------------------------------------------------------------------
extern "C" void kernel_launch(void* const* d_in, const int* in_sizes, int n_in,
                              void* d_out, int out_size, void* d_ws, size_t ws_size,
                              hipStream_t stream) {
    const float* attrs = (const float*)d_in[0];
    const float* W1    = (const float*)d_in[1];
    const float* b1    = (const float*)d_in[2];
    const float* W2    = (const float*)d_in[3];
    const float* b2    = (const float*)d_in[4];
    const float* W3    = (const float*)d_in[5];
    const float* b3    = (const float*)d_in[6];
    const int* edge_index = (const int*)d_in[7];
    const int* batch      = (const int*)d_in[8];
    float* out = (float*)d_out;

    unsigned short* buf0   = (unsigned short*)d_ws;             // N*64 bf16
    unsigned short* buf1   = buf0 + (size_t)N_NODES * DIM;      // N*64 bf16
    unsigned short* attrsb = buf1 + (size_t)N_NODES * DIM;      // N*64 bf16
    unsigned short* pW1  = attrsb + (size_t)N_NODES * DIM;      // 24576
    unsigned short* pW2  = pW1 + 24576;                         // 49152
    unsigned short* pW3  = pW2 + 49152;                         // 24576
    float* psums  = (float*)(pW3 + 24576);                      // G*64 f32
    int* offsets  = (int*)(psums + NGRAPH * DIM);               // N+1
    unsigned short* csr16 = (unsigned short*)(offsets + N_NODES + 1);  // E u16
    unsigned short* rank  = csr16 + N_EDGES;                    // E u16
    int* counts   = (int*)(rank + N_EDGES);                     // N
    int* bsum     = counts + N_NODES;                           // SCAN_NB

    const int* src = edge_index;
    const int* dst = edge_index + N_EDGES;

    const int pair_blocks = (N_EDGES / 2 + 255) / 256;
    const int gnn_blocks  = N_NODES / 16;                       // 3125, exact
    const int cvt_blocks  = (N_NODES * DIM / 8 + 255) / 256;

    // ---- one-time prep ----
    hipMemsetAsync(counts, 0, (size_t)N_NODES * sizeof(int), stream);
    hipMemsetAsync(psums, 0, (size_t)NGRAPH * DIM * sizeof(float), stream);
    cvt_kernel<<<cvt_blocks, 256, 0, stream>>>(attrs, attrsb);
    count_kernel<<<pair_blocks, 256, 0, stream>>>(dst, counts, rank);
    scan_partial_kernel<<<SCAN_NB, 256, 0, stream>>>(counts, bsum);
    scan_final_kernel<<<SCAN_NB, 256, 0, stream>>>(counts, bsum, offsets);
    place_kernel<<<pair_blocks, 256, 0, stream>>>(src, dst, rank, offsets, csr16);
    repack_all_kernel<<<48, 256, 0, stream>>>(W1, W2, W3, pW1, pW2, pW3);

    // ---- fused layers: attrsb -> buf0 -> buf1 -> psums (pool fused) ----
    for (int l = 0; l < LAYERS; ++l) {
        const unsigned short* w1 = pW1 + (size_t)l * 2 * 8 * 64 * 8;
        const unsigned short* w2 = pW2 + (size_t)l * 4 * 8 * 64 * 8;
        const unsigned short* w3 = pW3 + (size_t)l * 4 * 4 * 64 * 8;
        const float* bb1 = b1 + (size_t)l * HID;
        const float* bb2 = b2 + (size_t)l * HID;
        const float* bb3 = b3 + (size_t)l * DIM;
        if (l == 0)
            gnn_layer_kernel<false><<<gnn_blocks, 256, 0, stream>>>(
                attrsb, offsets, csr16, w1, bb1, w2, bb2, w3, bb3,
                buf0, nullptr, nullptr);
        else if (l == 1)
            gnn_layer_kernel<false><<<gnn_blocks, 256, 0, stream>>>(
                buf0, offsets, csr16, w1, bb1, w2, bb2, w3, bb3,
                buf1, nullptr, nullptr);
        else
            gnn_layer_kernel<true><<<gnn_blocks, 256, 0, stream>>>(
                buf1, offsets, csr16, w1, bb1, w2, bb2, w3, bb3,
                nullptr, batch, psums);
    }

    // ---- finalize mean pool ----
    pool_final_kernel<<<NGRAPH, DIM, 0, stream>>>(psums, batch, out);
}